// Round 1
// baseline (289.118 us; speedup 1.0000x reference)
//
#include <hip/hip_runtime.h>

#define DTC 0.2f
#define EPSC 1e-8f

// ---------------------------------------------------------------------------
// Prelude: dur[j] and dl_factor[j] depend only on ego[1,:,8:16] — constant
// across the batch. Compute once into d_ws (8 floats).
// ---------------------------------------------------------------------------
__global__ void sfm_pre(const float* __restrict__ ego,
                        const float* __restrict__ dl_wi,
                        const float* __restrict__ dl_bi,
                        const float* __restrict__ dl_wo,
                        const float* __restrict__ dl_bo,
                        float* __restrict__ ws) {
    int j = threadIdx.x;
    if (j >= 8) return;
    const float* base = ego + 51;              // ego[1,0,0]; row stride 17
    float idv = base[2 * 17 + 8 + j];          // ids_last[j] = ego[1,2,8+j]
    float dur = 0.f;
    for (int t = 0; t < 3; ++t) {
        bool found = false;
        for (int m = 0; m < 8; ++m) found = found || (idv == base[t * 17 + 8 + m]);
        dur += found ? 1.f : 0.f;
    }
    // mono_dl(dur)
    float acc = 0.f;
    for (int k = 0; k < 32; ++k) {
        float h = fmaxf(0.f, -(dl_wi[k] * dur + dl_bi[k]));
        acc = fmaf(dl_wo[k], h, acc);
    }
    ws[j] = acc + dl_bo[0];
}

// ---------------------------------------------------------------------------
// Main: one thread per batch row.
// ---------------------------------------------------------------------------
__global__ __launch_bounds__(256) void sfm_main(
    const float* __restrict__ ego, const float* __restrict__ nei,
    const float* __restrict__ border, const float* __restrict__ adp,
    const float* __restrict__ eang,
    const float* __restrict__ an_wi, const float* __restrict__ an_bi,
    const float* __restrict__ an_wo, const float* __restrict__ an_bo,
    const float* __restrict__ rn_wi, const float* __restrict__ rn_bi,
    const float* __restrict__ rn_wo, const float* __restrict__ rn_bo,
    const float* __restrict__ rb_wi, const float* __restrict__ rb_bi,
    const float* __restrict__ rb_wo, const float* __restrict__ rb_bo,
    const float* __restrict__ dlf,
    float* __restrict__ out, int Bn)
{
    // LDS: 9x32 weight vectors + dl factors + scalars
    __shared__ float sw[9 * 32 + 16];
    int t = threadIdx.x;
    if (t < 32) {
        sw[t]        = an_wi[t]; sw[32 + t]  = an_bi[t]; sw[64 + t]  = an_wo[t];
        sw[96 + t]   = rn_wi[t]; sw[128 + t] = rn_bi[t]; sw[160 + t] = rn_wo[t];
        sw[192 + t]  = rb_wi[t]; sw[224 + t] = rb_bi[t]; sw[256 + t] = rb_wo[t];
    }
    if (t >= 32 && t < 40) sw[288 + (t - 32)] = dlf[t - 32];
    if (t == 40) sw[296] = an_bo[0];
    if (t == 41) sw[297] = rn_bo[0];
    if (t == 42) sw[298] = rb_bo[0];
    if (t == 43) sw[299] = adp[0];
    if (t == 44) sw[300] = adp[1];
    if (t == 45) sw[301] = eang[0];
    if (t == 46) sw[302] = border[0];
    if (t == 47) sw[303] = border[3];
    __syncthreads();

    int b = blockIdx.x * 256 + t;
    if (b >= Bn) return;

    // ego_last = ego[b, 2, :]; we need indices 0..5 (flat offset b*51 + 34)
    const float* eg = ego + (long long)b * 51 + 34;
    float g0 = eg[0], g1 = eg[1], g2 = eg[2], g3 = eg[3], g4 = eg[4], g5 = eg[5];

    // neighbors: nei[b, j, 2..5]
    float rx[8], ry[8], rno[8], bb[8], mfx[8], mfy[8];
    const float* nb = nei + (long long)b * 136 + 2;
#pragma unroll
    for (int j = 0; j < 8; ++j) {
        float nx = nb[j * 17 + 0];
        float ny = nb[j * 17 + 1];
        float vx = nb[j * 17 + 2];
        float vy = nb[j * 17 + 3];
        mfx[j] = (nx == 0.f) ? 0.f : 1.f;   // mask: nei pos component == 0
        mfy[j] = (ny == 0.f) ? 0.f : 1.f;
        float Rx = nx - g2, Ry = ny - g3;
        rx[j] = Rx; ry[j] = Ry;
        float rr = sqrtf(Rx * Rx + Ry * Ry);
        rno[j] = rr;
        float ax = fmaf(vx, DTC, Rx), ay = fmaf(vy, DTC, Ry);
        float wx = vx * DTC, wy = vy * DTC;
        float bval = rr + (ax * ax + ay * ay) - (wx * wx + wy * wy);
        bb[j] = sqrtf(bval) * 0.5f;
    }

    // mono MLPs: k-outer (weights read once), neighbor-inner
    float accA[8], accR[8];
#pragma unroll
    for (int j = 0; j < 8; ++j) { accA[j] = 0.f; accR[j] = 0.f; }
    float rb0 = g3 - sw[302], rb1 = g3 - sw[303];
    float rbn0 = fabsf(rb0), rbn1 = fabsf(rb1);
    float accB0 = 0.f, accB1 = 0.f;
#pragma unroll 4
    for (int k = 0; k < 32; ++k) {
        float awi = sw[k],       abi  = sw[32 + k],  awo = sw[64 + k];
        float rwi = sw[96 + k],  rbi  = sw[128 + k], rwo = sw[160 + k];
        float bwi = sw[192 + k], bbi2 = sw[224 + k], bwo = sw[256 + k];
#pragma unroll
        for (int j = 0; j < 8; ++j) {
            float h = fmaxf(0.f, -fmaf(awi, rno[j], abi));
            accA[j] = fmaf(awo, h, accA[j]);
            float g = fmaxf(0.f, -fmaf(rwi, bb[j], rbi));
            accR[j] = fmaf(rwo, g, accR[j]);
        }
        float h0 = fmaxf(0.f, -fmaf(bwi, rbn0, bbi2)); accB0 = fmaf(bwo, h0, accB0);
        float h1 = fmaxf(0.f, -fmaf(bwi, rbn1, bbi2)); accB1 = fmaf(bwo, h1, accB1);
    }

    float an_bo_v = sw[296], rn_bo_v = sw[297], rb_bo_v = sw[298];
    float p0 = sw[299], p1 = sw[300], ang = sw[301];

    // e = normalize(ego_last[4:6])
    float elen = sqrtf(g4 * g4 + g5 * g5);
    float ex = g4 / elen, ey = g5 / elen;
    float na = fmaxf(sqrtf(ex * ex + ey * ey), EPSC);

    float axs = 0.f, ays = 0.f;
#define CLAMP_ADD(VX, VY)                                                   \
    {                                                                       \
        float _vx = (VX), _vy = (VY);                                       \
        float _nv = fmaxf(sqrtf(_vx * _vx + _vy * _vy), EPSC);              \
        float _c = (ex * _vx + ey * _vy) / (na * _nv);                      \
        if (fabsf(_c) > ang) { axs += _vx; ays += _vy; }                    \
    }

    // f_dest (one row): v34 = (g3, g4); dv = (|v34|, 0)
    {
        float dvn = sqrtf(g3 * g3 + g4 * g4);
        float fdx = (p1 * dvn - g3) / p0;
        float fdy = (0.f - g4) / p0;
        CLAMP_ADD(fdx, fdy);
    }
    // f_attr rows
#pragma unroll
    for (int j = 0; j < 8; ++j) {
        float coef = (accA[j] + an_bo_v) / rno[j] * sw[288 + j];
        CLAMP_ADD(coef * rx[j] * mfx[j], coef * ry[j] * mfy[j]);
    }
    // f_repu rows
#pragma unroll
    for (int j = 0; j < 8; ++j) {
        float coef = (accR[j] + rn_bo_v) / rno[j];
        CLAMP_ADD(coef * rx[j] * mfx[j], coef * ry[j] * mfy[j]);
    }
    // f_bor rows: (0, mono_rb(|rbv|) * sign(rbv))
    {
        float f0 = (accB0 + rb_bo_v) * (rb0 / rbn0);
        float f1 = (accB1 + rb_bo_v) * (rb1 / rbn1);
        CLAMP_ADD(0.f, f0);
        CLAMP_ADD(0.f, f1);
    }
#undef CLAMP_ADD

    float vxo = fmaf(axs, DTC, g2);
    float vyo = fmaf(ays, DTC, g3);
    float sx  = fmaf(vxo, DTC, g0);
    float sy  = fmaf(vyo, DTC, g1);

    float* op = out + (long long)b * 6;
    op[0] = sx;  op[1] = sy;
    op[2] = vxo; op[3] = vyo;
    op[4] = axs; op[5] = ays;
}

extern "C" void kernel_launch(void* const* d_in, const int* in_sizes, int n_in,
                              void* d_out, int out_size, void* d_ws, size_t ws_size,
                              hipStream_t stream) {
    const float* ego    = (const float*)d_in[0];
    const float* nei    = (const float*)d_in[1];
    const float* border = (const float*)d_in[2];
    const float* adp    = (const float*)d_in[3];
    const float* eang   = (const float*)d_in[4];
    const float* an_wi  = (const float*)d_in[5];
    const float* an_bi  = (const float*)d_in[6];
    const float* an_wo  = (const float*)d_in[7];
    const float* an_bo  = (const float*)d_in[8];
    const float* rn_wi  = (const float*)d_in[9];
    const float* rn_bi  = (const float*)d_in[10];
    const float* rn_wo  = (const float*)d_in[11];
    const float* rn_bo  = (const float*)d_in[12];
    const float* rb_wi  = (const float*)d_in[13];
    const float* rb_bi  = (const float*)d_in[14];
    const float* rb_wo  = (const float*)d_in[15];
    const float* rb_bo  = (const float*)d_in[16];
    const float* dl_wi  = (const float*)d_in[17];
    const float* dl_bi  = (const float*)d_in[18];
    const float* dl_wo  = (const float*)d_in[19];
    const float* dl_bo  = (const float*)d_in[20];
    float* out = (float*)d_out;
    float* ws  = (float*)d_ws;

    int Bn = in_sizes[0] / (3 * 17);

    sfm_pre<<<1, 64, 0, stream>>>(ego, dl_wi, dl_bi, dl_wo, dl_bo, ws);

    int grid = (Bn + 255) / 256;
    sfm_main<<<grid, 256, 0, stream>>>(ego, nei, border, adp, eang,
                                       an_wi, an_bi, an_wo, an_bo,
                                       rn_wi, rn_bi, rn_wo, rn_bo,
                                       rb_wi, rb_bi, rb_wo, rb_bo,
                                       ws, out, Bn);
}

// Round 2
// 278.844 us; speedup vs baseline: 1.0368x; 1.0368x over previous
//
#include <hip/hip_runtime.h>

#define DTC 0.2f
#define EPSC 1e-8f

// ---------------------------------------------------------------------------
// Prelude: dur[j] / dl_factor[j] depend only on ego[1,:,8:16] — constant
// across the batch. 256 threads: thread = (j = t>>5, k = t&31); one MLP term
// each, shuffle-reduce over 32 lanes. Writes 8 floats to ws.
// ---------------------------------------------------------------------------
__global__ void sfm_pre(const float* __restrict__ ego,
                        const float* __restrict__ dl_wi,
                        const float* __restrict__ dl_bi,
                        const float* __restrict__ dl_wo,
                        const float* __restrict__ dl_bo,
                        float* __restrict__ ws) {
    int t = threadIdx.x;
    int j = t >> 5, k = t & 31;
    const float* base = ego + 51;              // ego[1,0,0]; row stride 17
    float idv = base[2 * 17 + 8 + j];          // ids_last[j]
    float dur = 0.f;
    for (int tt = 0; tt < 3; ++tt) {
        bool f = false;
        for (int m = 0; m < 8; ++m) f = f || (idv == base[tt * 17 + 8 + m]);
        dur += f ? 1.f : 0.f;
    }
    float part = dl_wo[k] * fmaxf(0.f, -fmaf(dl_wi[k], dur, dl_bi[k]));
#pragma unroll
    for (int m = 1; m < 32; m <<= 1) part += __shfl_xor(part, m, 64);
    if (k == 0) ws[j] = part + dl_bo[0];
}

// ---------------------------------------------------------------------------
// Main: 8 lanes per row (one per neighbor record). 256 threads = 32 rows.
// ---------------------------------------------------------------------------
__global__ __launch_bounds__(256) void sfm_main(
    const float* __restrict__ ego, const float* __restrict__ nei,
    const float* __restrict__ border, const float* __restrict__ adp,
    const float* __restrict__ eang,
    const float* __restrict__ an_wi, const float* __restrict__ an_bi,
    const float* __restrict__ an_wo, const float* __restrict__ an_bo,
    const float* __restrict__ rn_wi, const float* __restrict__ rn_bi,
    const float* __restrict__ rn_wo, const float* __restrict__ rn_bo,
    const float* __restrict__ rb_wi, const float* __restrict__ rb_bi,
    const float* __restrict__ rb_wo, const float* __restrict__ rb_bo,
    const float* __restrict__ dlf,
    float* __restrict__ out, int Bn)
{
    __shared__ float sw[304];
    int t = threadIdx.x;
    if (t < 32) {
        sw[t]        = an_wi[t]; sw[32 + t]  = an_bi[t]; sw[64 + t]  = an_wo[t];
        sw[96 + t]   = rn_wi[t]; sw[128 + t] = rn_bi[t]; sw[160 + t] = rn_wo[t];
        sw[192 + t]  = rb_wi[t]; sw[224 + t] = rb_bi[t]; sw[256 + t] = rb_wo[t];
    }
    if (t >= 32 && t < 40) sw[288 + (t - 32)] = dlf[t - 32];
    if (t == 40) sw[296] = an_bo[0];
    if (t == 41) sw[297] = rn_bo[0];
    if (t == 42) sw[298] = rb_bo[0];
    if (t == 43) sw[299] = adp[0];
    if (t == 44) sw[300] = adp[1];
    if (t == 45) sw[301] = eang[0];
    if (t == 46) sw[302] = border[0];
    if (t == 47) sw[303] = border[3];
    __syncthreads();

    int l = t & 7;                                  // record index
    long long row = (long long)blockIdx.x * 32 + (t >> 3);
    if (row >= Bn) return;

    // --- ego fields: lanes 0..5 load g0..g5, broadcast via shuffle ---------
    float egv = 0.f;
    if (l < 6) egv = ego[row * 51 + 34 + l];
    int lb = (t & 63) & ~7;                         // group base lane in wave
    float g0 = __shfl(egv, lb + 0, 64);
    float g1 = __shfl(egv, lb + 1, 64);
    float g2 = __shfl(egv, lb + 2, 64);
    float g3 = __shfl(egv, lb + 3, 64);
    float g4 = __shfl(egv, lb + 4, 64);
    float g5 = __shfl(egv, lb + 5, 64);

    // --- this lane's neighbor record: fields 2..5 --------------------------
    const float* nr = nei + row * 136 + l * 17 + 2;
    float nx = nr[0], ny = nr[1], vx = nr[2], vy = nr[3];

    float Rx = nx - g2, Ry = ny - g3;
    float rr = sqrtf(Rx * Rx + Ry * Ry);
    float ax = fmaf(vx, DTC, Rx), ay = fmaf(vy, DTC, Ry);
    float wx = vx * DTC, wy = vy * DTC;
    float bb = sqrtf(rr + ax * ax + ay * ay - wx * wx - wy * wy) * 0.5f;

    float rb0 = g3 - sw[302], rb1 = g3 - sw[303];
    float rbn0 = fabsf(rb0), rbn1 = fabsf(rb1);

    // --- mono MLPs: this lane's record (attr + repu), k-strided border -----
    float accA = 0.f, accR = 0.f;
#pragma unroll 8
    for (int k = 0; k < 32; ++k) {
        float h = fmaxf(0.f, -fmaf(sw[k], rr, sw[32 + k]));
        accA = fmaf(sw[64 + k], h, accA);
        float g = fmaxf(0.f, -fmaf(sw[96 + k], bb, sw[128 + k]));
        accR = fmaf(sw[160 + k], g, accR);
    }
    float pB0 = 0.f, pB1 = 0.f;
#pragma unroll
    for (int m = 0; m < 4; ++m) {
        int k = l + 8 * m;
        float bwi = sw[192 + k], bbi = sw[224 + k], bwo = sw[256 + k];
        pB0 = fmaf(bwo, fmaxf(0.f, -fmaf(bwi, rbn0, bbi)), pB0);
        pB1 = fmaf(bwo, fmaxf(0.f, -fmaf(bwi, rbn1, bbi)), pB1);
    }

    float an_bo_v = sw[296], rn_bo_v = sw[297], rb_bo_v = sw[298];
    float p0 = sw[299], p1 = sw[300], ang = sw[301];

    // e = normalize(ego_last[4:6])
    float elen = sqrtf(g4 * g4 + g5 * g5);
    float ex = g4 / elen, ey = g5 / elen;
    float na = fmaxf(sqrtf(ex * ex + ey * ey), EPSC);

    float axs = 0.f, ays = 0.f;
#define CLAMP_ADD(VX, VY)                                                   \
    {                                                                       \
        float _vx = (VX), _vy = (VY);                                       \
        float _nv = fmaxf(sqrtf(_vx * _vx + _vy * _vy), EPSC);              \
        float _c = (ex * _vx + ey * _vy) / (na * _nv);                      \
        if (fabsf(_c) > ang) { axs += _vx; ays += _vy; }                    \
    }

    float mfx = (nx == 0.f) ? 0.f : 1.f;
    float mfy = (ny == 0.f) ? 0.f : 1.f;

    // f_attr for this record
    {
        float coef = (accA + an_bo_v) / rr * sw[288 + l];
        CLAMP_ADD(coef * Rx * mfx, coef * Ry * mfy);
    }
    // f_repu for this record
    {
        float coef = (accR + rn_bo_v) / rr;
        CLAMP_ADD(coef * Rx * mfx, coef * Ry * mfy);
    }

    // --- reduce over the 8 lanes of the row --------------------------------
#pragma unroll
    for (int m = 1; m < 8; m <<= 1) {
        axs += __shfl_xor(axs, m, 64);
        ays += __shfl_xor(ays, m, 64);
        pB0 += __shfl_xor(pB0, m, 64);
        pB1 += __shfl_xor(pB1, m, 64);
    }

    if (l == 0) {
        // f_dest
        float dvn = sqrtf(g3 * g3 + g4 * g4);
        CLAMP_ADD((p1 * dvn - g3) / p0, -g4 / p0);
        // f_bor rows: (0, mono_rb(|rbv|) * sign(rbv))
        float f0 = (pB0 + rb_bo_v) * (rb0 / rbn0);
        float f1 = (pB1 + rb_bo_v) * (rb1 / rbn1);
        CLAMP_ADD(0.f, f0);
        CLAMP_ADD(0.f, f1);

        float vxo = fmaf(axs, DTC, g2);
        float vyo = fmaf(ays, DTC, g3);
        float* op = out + row * 6;
        op[0] = fmaf(vxo, DTC, g0);
        op[1] = fmaf(vyo, DTC, g1);
        op[2] = vxo; op[3] = vyo;
        op[4] = axs; op[5] = ays;
    }
#undef CLAMP_ADD
}

extern "C" void kernel_launch(void* const* d_in, const int* in_sizes, int n_in,
                              void* d_out, int out_size, void* d_ws, size_t ws_size,
                              hipStream_t stream) {
    const float* ego    = (const float*)d_in[0];
    const float* nei    = (const float*)d_in[1];
    const float* border = (const float*)d_in[2];
    const float* adp    = (const float*)d_in[3];
    const float* eang   = (const float*)d_in[4];
    const float* an_wi  = (const float*)d_in[5];
    const float* an_bi  = (const float*)d_in[6];
    const float* an_wo  = (const float*)d_in[7];
    const float* an_bo  = (const float*)d_in[8];
    const float* rn_wi  = (const float*)d_in[9];
    const float* rn_bi  = (const float*)d_in[10];
    const float* rn_wo  = (const float*)d_in[11];
    const float* rn_bo  = (const float*)d_in[12];
    const float* rb_wi  = (const float*)d_in[13];
    const float* rb_bi  = (const float*)d_in[14];
    const float* rb_wo  = (const float*)d_in[15];
    const float* rb_bo  = (const float*)d_in[16];
    const float* dl_wi  = (const float*)d_in[17];
    const float* dl_bi  = (const float*)d_in[18];
    const float* dl_wo  = (const float*)d_in[19];
    const float* dl_bo  = (const float*)d_in[20];
    float* out = (float*)d_out;
    float* ws  = (float*)d_ws;

    int Bn = in_sizes[0] / (3 * 17);

    sfm_pre<<<1, 256, 0, stream>>>(ego, dl_wi, dl_bi, dl_wo, dl_bo, ws);

    int grid = (Bn + 31) / 32;
    sfm_main<<<grid, 256, 0, stream>>>(ego, nei, border, adp, eang,
                                       an_wi, an_bi, an_wo, an_bo,
                                       rn_wi, rn_bi, rn_wo, rn_bo,
                                       rb_wi, rb_bi, rb_wo, rb_bo,
                                       ws, out, Bn);
}